// Round 6
// baseline (1023.563 us; speedup 1.0000x reference)
//
#include <hip/hip_runtime.h>
#include <cstdint>
#include <cstddef>

typedef short short8 __attribute__((ext_vector_type(8)));
typedef float floatx4 __attribute__((ext_vector_type(4)));
typedef unsigned short ushort4v __attribute__((ext_vector_type(4)));
typedef unsigned short ushort2v __attribute__((ext_vector_type(2)));

#define AS1C(p) ((const __attribute__((address_space(1))) void*)(p))
#define AS3(p)  ((__attribute__((address_space(3))) void*)(p))

// round-to-nearest-even float -> bf16 bits
__device__ __forceinline__ unsigned short f2bf(float f) {
    union { float f; unsigned int u; } v; v.f = f;
    unsigned int u = v.u;
    unsigned int r = (u + 0x7fffu + ((u >> 16) & 1u)) >> 16;
    return (unsigned short)r;
}

__device__ __forceinline__ float bf2f(unsigned short b) {
    union { unsigned int u; float f; } v;
    v.u = (unsigned int)b << 16;
    return v.f;
}

__device__ __forceinline__ float wave_sum(float s) {
#pragma unroll
    for (int off = 32; off > 0; off >>= 1)
        s += __shfl_xor(s, off, 64);
    return s;
}

// ---------------------------------------------------------------------------
// Kernel 1: per-row l2norm of feats -> fb (bf16); slot-assign directly:
// pos = atomicAdd(cnt[lab]) gives each row a unique slot in idx2[lab][512].
// One wave (64 lanes) per row of D=512.  (verified r5)
// ---------------------------------------------------------------------------
__global__ __launch_bounds__(256) void k_norm(
    const float* __restrict__ feats, const int* __restrict__ labels,
    unsigned short* __restrict__ fb, int* __restrict__ cnt,
    int* __restrict__ idx2, int N)
{
    const int gw   = (int)((blockIdx.x * 256u + threadIdx.x) >> 6);
    const int lane = threadIdx.x & 63;
    if (gw >= N) return;

    const float* row = feats + (size_t)gw * 512;
    floatx4 x0 = *(const floatx4*)(row + lane * 4);
    floatx4 x1 = *(const floatx4*)(row + 256 + lane * 4);

    float s = x0.x * x0.x + x0.y * x0.y + x0.z * x0.z + x0.w * x0.w
            + x1.x * x1.x + x1.y * x1.y + x1.z * x1.z + x1.w * x1.w;
    s = wave_sum(s);
    const float inv = 1.0f / fmaxf(sqrtf(s), 1e-12f);

    floatx4 y0 = x0 * inv, y1 = x1 * inv;

    ushort4v b0, b1;
    b0.x = f2bf(y0.x); b0.y = f2bf(y0.y); b0.z = f2bf(y0.z); b0.w = f2bf(y0.w);
    b1.x = f2bf(y1.x); b1.y = f2bf(y1.y); b1.z = f2bf(y1.z); b1.w = f2bf(y1.w);
    *(ushort4v*)(fb + (size_t)gw * 512 + lane * 4)       = b0;
    *(ushort4v*)(fb + (size_t)gw * 512 + 256 + lane * 4) = b1;

    if (lane == 0) {
        const int lab = labels[gw];
        const int pos = atomicAdd(cnt + lab, 1);
        // Poisson(64) max ~110 << 512; clamp guards memory regardless.
        if (pos < 512) idx2[lab * 512 + pos] = gw;
    }
}

// ---------------------------------------------------------------------------
// Kernel 2: per-class gather segment-mean FROM fb (bf16, already normalized)
// + EMA + renorm; write pb (bf16). One block per class.  (verified r5)
// ---------------------------------------------------------------------------
__global__ __launch_bounds__(256) void k_segsum_update(
    const unsigned short* __restrict__ fb, const int* __restrict__ idx2,
    const int* __restrict__ cnt, const float* __restrict__ protos,
    unsigned short* __restrict__ pb)
{
    const int c = blockIdx.x;
    const int t = threadIdx.x;
    const int n  = cnt[c];
    const int nr = n < 512 ? n : 512;
    const int* lst = idx2 + c * 512;

    float a0 = 0.0f, a1 = 0.0f;
    int j = 0;
    for (; j + 4 <= nr; j += 4) {
        const int4 r = *(const int4*)(lst + j);
        const ushort2v v0 = *(const ushort2v*)(fb + (size_t)r.x * 512 + t * 2);
        const ushort2v v1 = *(const ushort2v*)(fb + (size_t)r.y * 512 + t * 2);
        const ushort2v v2 = *(const ushort2v*)(fb + (size_t)r.z * 512 + t * 2);
        const ushort2v v3 = *(const ushort2v*)(fb + (size_t)r.w * 512 + t * 2);
        a0 += bf2f(v0.x) + bf2f(v1.x) + bf2f(v2.x) + bf2f(v3.x);
        a1 += bf2f(v0.y) + bf2f(v1.y) + bf2f(v2.y) + bf2f(v3.y);
    }
    for (; j < nr; ++j) {
        const int r = lst[j];
        const ushort2v v = *(const ushort2v*)(fb + (size_t)r * 512 + t * 2);
        a0 += bf2f(v.x);
        a1 += bf2f(v.y);
    }

    const float2 p = *(const float2*)(protos + (size_t)c * 512 + t * 2);
    const float rc = 0.1f / fmaxf((float)n, 1.0f);
    const float v0 = 0.9f * p.x + rc * a0;
    const float v1 = 0.9f * p.y + rc * a1;

    __shared__ float red[256];
    red[t] = v0 * v0 + v1 * v1;
    __syncthreads();
#pragma unroll
    for (int off = 128; off > 0; off >>= 1) {
        if (t < off) red[t] += red[t + off];
        __syncthreads();
    }
    const float inv = 1.0f / fmaxf(sqrtf(red[0]), 1e-12f);

    float o0, o1;
    if (n > 0) { o0 = v0 * inv; o1 = v1 * inv; }
    else       { o0 = p.x;      o1 = p.y;      }

    ushort2v b;
    b.x = f2bf(o0);
    b.y = f2bf(o1);
    *(ushort2v*)(pb + (size_t)c * 512 + t * 2) = b;
}

// ---------------------------------------------------------------------------
// Kernel 3: sim[N,C] = f[N,512] @ P[C,512]^T, bf16 in, fp32 out.
// 256x256 tile, BK=32, 512 threads (8 waves: 2M x 4N, each 128x64 out).
// Same verified 8-phase-skeleton schedule as r4/r5, rescaled to BK=32:
//   LDS = 2 buf x 4 slots x (128x32 bf16 = 8 KB) = 64 KB  -> 2 blocks/CU
//   (r4 used 128 KB -> 1 block/CU; the 2nd resident block overlaps
//   prologue fill, barrier stalls and epilogue store-drain).
// STAGE = exactly 1 global_load_lds x16B per thread (512*16B = 8 KB slot).
// Ledger (1 load per STAGE): prologue 7 STAGEs, vmcnt(3) -> tile0 landed.
//   kt p0: stage Ah1(kt+1)->buf^1; p1: Bh0(kt+2)->buf; p2: Bh1(kt+2)->buf;
//   kt p3: stage Ah0(kt+2)->buf; vmcnt(3) retires exactly kt+1's 4 units.
//   tail (kt+2>=NT): vmcnt(0) drain (same fix point as the r3->r4 bug).
// No LDS swizzle needed at BK=32: rows are 64 B, so even rows occupy banks
// 0-15 and odd rows 16-31; a b128 column-slice read puts 8 lanes on each
// 4-bank group = the ds_read_b128 floor (verified by per-lane bank arith).
// WAR safety identical to r4: each slot overwrite is issued after the
// end-of-phase barrier that followed its last reader's lgkmcnt(0)
// (A-quad3 prefetch at p2 frees the A slot before p3's overwrite).
// ---------------------------------------------------------------------------
__global__ __launch_bounds__(512, 4) void k_gemm(
    const unsigned short* __restrict__ A, const unsigned short* __restrict__ B,
    float* __restrict__ out, int N, int C)
{
    constexpr int K  = 512;
    constexpr int NT = 16;                          // K / 32
    __shared__ unsigned short lds[2][4][128 * 32];  // 64 KB

    const int tid  = threadIdx.x;
    const int lane = tid & 63;
    const int wid  = tid >> 6;        // 0..7
    const int wm   = wid >> 2;        // 0..1  M-half
    const int wn   = wid & 3;         // 0..3  N-quarter
    const int quad = lane >> 4, l16 = lane & 15;
    const int lofs = l16 * 32 + quad * 8;   // linear: row l16, k-cols quad*8..+7
    const int bRow = (wn & 1) * 4;          // B 16-row-group base within slot

    const size_t m0 = (size_t)blockIdx.y * 256;
    const size_t n0 = (size_t)blockIdx.x * 256;

    // stage mapping: thread tid loads global (row tid>>2, col (tid&3)*8)
    // of the 128x32 slot; LDS dest is linear tid*16 B.
    const int preOfs = (tid >> 2) * K + (tid & 3) * 8;
    const int dstOfs = tid * 8;

#define STAGE(mat, rowbase, k0, slotp)                                          \
    __builtin_amdgcn_global_load_lds(                                           \
        AS1C((mat) + (size_t)(rowbase) * K + (k0) + preOfs),                    \
        AS3((slotp) + dstOfs), 16, 0, 0)

    floatx4 acc[8][4];
#pragma unroll
    for (int m = 0; m < 8; ++m)
#pragma unroll
        for (int n = 0; n < 4; ++n)
            acc[m][n] = (floatx4){0.0f, 0.0f, 0.0f, 0.0f};

#define MFMA8(R0, AR)                                                           \
    _Pragma("unroll")                                                           \
    for (int m_ = 0; m_ < 2; ++m_)                                              \
        _Pragma("unroll")                                                       \
        for (int n_ = 0; n_ < 4; ++n_)                                          \
            acc[(R0) + m_][n_] = __builtin_amdgcn_mfma_f32_16x16x32_bf16(       \
                AR[m_], bfr[n_], acc[(R0) + m_][n_], 0, 0, 0)

#define GTILE(KT, BUF, P0STAGE, KT2STAGE) do {                                  \
    const unsigned short* sA = &lds[BUF][wm][0];                                \
    const unsigned short* sB = &lds[BUF][2 + (wn >> 1)][0];                     \
    short8 bfr[4], ac[2], a3[2];                                                \
    /* p0: read B(all)+A-q0; stage Ah1(KT+1)->buf^1; MFMA rows 0-1 */           \
    _Pragma("unroll")                                                           \
    for (int n_ = 0; n_ < 4; ++n_)                                              \
        bfr[n_] = *(const short8*)(sB + ((bRow + n_) << 9) + lofs);             \
    _Pragma("unroll")                                                           \
    for (int m_ = 0; m_ < 2; ++m_)                                              \
        ac[m_] = *(const short8*)(sA + (m_ << 9) + lofs);                       \
    if (P0STAGE) STAGE(A, m0 + 128, ((KT) + 1) * 32, &lds[(BUF) ^ 1][1][0]);    \
    __builtin_amdgcn_s_barrier();                                               \
    asm volatile("s_waitcnt lgkmcnt(0)" ::: "memory");                          \
    __builtin_amdgcn_sched_barrier(0);                                          \
    __builtin_amdgcn_s_setprio(1);                                              \
    MFMA8(0, ac);                                                               \
    __builtin_amdgcn_s_setprio(0);                                              \
    __builtin_amdgcn_sched_barrier(0);                                          \
    __builtin_amdgcn_s_barrier();                                               \
    /* p1: read A-q1; stage Bh0(KT+2)->buf; MFMA rows 2-3 */                    \
    _Pragma("unroll")                                                           \
    for (int m_ = 0; m_ < 2; ++m_)                                              \
        ac[m_] = *(const short8*)(sA + ((2 + m_) << 9) + lofs);                 \
    if (KT2STAGE) STAGE(B, n0, ((KT) + 2) * 32, &lds[BUF][2][0]);               \
    __builtin_amdgcn_s_barrier();                                               \
    asm volatile("s_waitcnt lgkmcnt(0)" ::: "memory");                          \
    __builtin_amdgcn_sched_barrier(0);                                          \
    __builtin_amdgcn_s_setprio(1);                                              \
    MFMA8(2, ac);                                                               \
    __builtin_amdgcn_s_setprio(0);                                              \
    __builtin_amdgcn_sched_barrier(0);                                          \
    __builtin_amdgcn_s_barrier();                                               \
    /* p2: read A-q2 + prefetch A-q3; stage Bh1(KT+2)->buf; MFMA rows 4-5 */    \
    _Pragma("unroll")                                                           \
    for (int m_ = 0; m_ < 2; ++m_)                                              \
        ac[m_] = *(const short8*)(sA + ((4 + m_) << 9) + lofs);                 \
    _Pragma("unroll")                                                           \
    for (int m_ = 0; m_ < 2; ++m_)                                              \
        a3[m_] = *(const short8*)(sA + ((6 + m_) << 9) + lofs);                 \
    if (KT2STAGE) STAGE(B, n0 + 128, ((KT) + 2) * 32, &lds[BUF][3][0]);         \
    __builtin_amdgcn_s_barrier();                                               \
    asm volatile("s_waitcnt lgkmcnt(0)" ::: "memory");                          \
    __builtin_amdgcn_sched_barrier(0);                                          \
    __builtin_amdgcn_s_setprio(1);                                              \
    MFMA8(4, ac);                                                               \
    __builtin_amdgcn_s_setprio(0);                                              \
    __builtin_amdgcn_sched_barrier(0);                                          \
    __builtin_amdgcn_s_barrier();                                               \
    /* p3: stage Ah0(KT+2); counted/drain vmcnt; MFMA rows 6-7 (from a3) */     \
    if (KT2STAGE) {                                                             \
        STAGE(A, m0, ((KT) + 2) * 32, &lds[BUF][0][0]);                         \
        asm volatile("s_waitcnt vmcnt(3)" ::: "memory");                        \
    } else {                                                                    \
        asm volatile("s_waitcnt vmcnt(0)" ::: "memory");                        \
    }                                                                           \
    __builtin_amdgcn_s_barrier();                                               \
    asm volatile("s_waitcnt lgkmcnt(0)" ::: "memory");                          \
    __builtin_amdgcn_sched_barrier(0);                                          \
    __builtin_amdgcn_s_setprio(1);                                              \
    MFMA8(6, a3);                                                               \
    __builtin_amdgcn_s_setprio(0);                                              \
    __builtin_amdgcn_sched_barrier(0);                                          \
    __builtin_amdgcn_s_barrier();                                               \
} while (0)

    // prologue: 7 units (tile0 complete + Bh0,Bh1,Ah0 of tile1)
    STAGE(B, n0,       0,  &lds[0][2][0]);
    STAGE(B, n0 + 128, 0,  &lds[0][3][0]);
    STAGE(A, m0,       0,  &lds[0][0][0]);
    STAGE(A, m0 + 128, 0,  &lds[0][1][0]);
    STAGE(B, n0,       32, &lds[1][2][0]);
    STAGE(B, n0 + 128, 32, &lds[1][3][0]);
    STAGE(A, m0,       32, &lds[1][0][0]);
    asm volatile("s_waitcnt vmcnt(3)" ::: "memory");   // tile0's 4 units landed
    __builtin_amdgcn_s_barrier();

    // main: tiles 0..13 fully staged (kt+2 <= 15); icache-friendly pair loop
#pragma unroll 1
    for (int kt = 0; kt < NT - 2; kt += 2) {
        GTILE(kt,     0, 1, 1);
        GTILE(kt + 1, 1, 1, 1);
    }
    // tail: tile 14 (stage Ah1(15) only; drain), tile 15 (no stages; drain)
    GTILE(NT - 2, 0, 1, 0);
    GTILE(NT - 1, 1, 0, 0);

#undef GTILE
#undef MFMA8
#undef STAGE

    // epilogue: C/D layout col=lane&15, row=(lane>>4)*4+reg
#pragma unroll
    for (int m = 0; m < 8; ++m) {
        const size_t r0 = m0 + (size_t)(wm * 128 + m * 16 + quad * 4);
#pragma unroll
        for (int n = 0; n < 4; ++n) {
            const size_t c = n0 + (size_t)(wn * 64 + n * 16 + l16);
#pragma unroll
            for (int r = 0; r < 4; ++r)
                out[(r0 + r) * (size_t)C + c] = acc[m][n][r];
        }
    }
}

// ---------------------------------------------------------------------------
extern "C" void kernel_launch(void* const* d_in, const int* in_sizes, int n_in,
                              void* d_out, int out_size, void* d_ws, size_t ws_size,
                              hipStream_t stream)
{
    const float* feats  = (const float*)d_in[0];
    const float* protos = (const float*)d_in[1];
    const int*   labels = (const int*)d_in[2];
    float* sim = (float*)d_out;

    const int D = 512;
    const int N = in_sizes[0] / D;   // 65536
    const int C = in_sizes[1] / D;   // 1024

    char* w = (char*)d_ws;
    unsigned short* fb = (unsigned short*)w;                 // N*D bf16 = 64 MB
    size_t off = (size_t)N * D * 2;
    unsigned short* pb = (unsigned short*)(w + off);         // C*D bf16 = 1 MB
    off += (size_t)C * D * 2;
    int* idx2 = (int*)(w + off);                             // C*512 i32 = 2 MB
    off += (size_t)C * 512 * 4;
    int* cnt = (int*)(w + off);                              // C i32

    hipMemsetAsync(cnt, 0, (size_t)C * 4, stream);

    k_norm<<<dim3(N / 4), dim3(256), 0, stream>>>(feats, labels, fb, cnt, idx2, N);
    k_segsum_update<<<dim3(C), dim3(256), 0, stream>>>(fb, idx2, cnt, protos, pb);

    dim3 g(C / 256, N / 256);   // (4, 256)
    k_gemm<<<g, dim3(512), 0, stream>>>(fb, pb, sim, N, C);
}